// Round 4
// baseline (150.457 us; speedup 1.0000x reference)
//
#include <hip/hip_runtime.h>
#include <stdint.h>

#define S_LEN 4096
#define NH    16
#define HD    64
#define RSTR  (NH * HD)   // seq-row stride in floats

typedef __attribute__((ext_vector_type(8))) __bf16 bf16x8;
typedef __attribute__((ext_vector_type(4))) short short4v;
typedef __attribute__((ext_vector_type(4))) float floatx4;

union BF4 { unsigned short u[4]; unsigned d[2]; short4v s; };

// pack two f32 -> bf16x2 (round-half-up) in one v_perm_b32
__device__ __forceinline__ unsigned pkbf(float a, float b) {
    unsigned ua = __builtin_bit_cast(unsigned, a) + 0x8000u;
    unsigned ub = __builtin_bit_cast(unsigned, b) + 0x8000u;
    return __builtin_amdgcn_perm(ub, ua, 0x07060302u);
}

__device__ __forceinline__ floatx4 mfma16(short4v a, short4v b, floatx4 c) {
#if __has_builtin(__builtin_amdgcn_mfma_f32_16x16x16bf16_1k)
    return __builtin_amdgcn_mfma_f32_16x16x16bf16_1k(a, b, c, 0, 0, 0);
#else
    floatx4 d;
    asm volatile("v_mfma_f32_16x16x16_bf16 %0, %1, %2, %3\n\ts_nop 7\n\ts_nop 7"
                 : "=v"(d) : "v"(a), "v"(b), "v"(c));
    return d;
#endif
}

// async global->LDS, 16B/lane
__device__ __forceinline__ void gl16(const void* g, void* l) {
#if __has_builtin(__builtin_amdgcn_global_load_lds)
    __builtin_amdgcn_global_load_lds((const __attribute__((address_space(1))) unsigned int*)g,
                                     (__attribute__((address_space(3))) unsigned int*)l, 16, 0, 0);
#else
    *(uint4*)l = *(const uint4*)g;
#endif
}

// ---------------- preprocess: K -> bf16 swizzled tiles, V -> V^T bf16 swizzled tiles
// tile(h,tau) = 64x64 bf16 = 8 KB, contiguous; element (r, c) at
// r*64 + ((c>>3)^(r&7))*8 + (c&7)  (XOR granule swizzle)
__global__ __launch_bounds__(256)
void pp_kv(const float* __restrict__ K, const float* __restrict__ V,
           unsigned short* __restrict__ Kz, unsigned short* __restrict__ Vz) {
    __shared__ __align__(16) float vt[64][68];   // +4 pad: 16B-aligned rows, read conflict-free
    const int bid = blockIdx.x;
    const int h   = bid & 15;
    const int tau = bid >> 4;
    const int tid = threadIdx.x;
    // K: thread (r = tid>>2, gg = tid&3) covers d = 16gg..16gg+15 of row r
    {
        const int r = tid >> 2, gg = tid & 3;
        const float* kp = K + ((size_t)(64 * tau + r) * NH + h) * HD + 16 * gg;
        const float4 a = *reinterpret_cast<const float4*>(kp);
        const float4 b = *reinterpret_cast<const float4*>(kp + 4);
        const float4 c = *reinterpret_cast<const float4*>(kp + 8);
        const float4 d = *reinterpret_cast<const float4*>(kp + 12);
        uint4 f0, f1;
        f0.x = pkbf(a.x, a.y); f0.y = pkbf(a.z, a.w);
        f0.z = pkbf(b.x, b.y); f0.w = pkbf(b.z, b.w);
        f1.x = pkbf(c.x, c.y); f1.y = pkbf(c.z, c.w);
        f1.z = pkbf(d.x, d.y); f1.w = pkbf(d.z, d.w);
        unsigned short* out = Kz + ((size_t)(h * 64 + tau)) * 4096 + r * 64;
        *reinterpret_cast<uint4*>(out + (((2 * gg)     ^ (r & 7)) * 8)) = f0;
        *reinterpret_cast<uint4*>(out + (((2 * gg + 1) ^ (r & 7)) * 8)) = f1;
    }
    // V: coalesced row loads -> LDS
    {
        const int r = tid >> 2, ch = tid & 3;
        const float* vrow = V + ((size_t)(64 * tau + r) * NH + h) * HD + 4 * ch;
        #pragma unroll
        for (int k2 = 0; k2 < 4; ++k2)
            *reinterpret_cast<float4*>(&vt[r][4 * ch + 16 * k2]) =
                *reinterpret_cast<const float4*>(vrow + 16 * k2);
    }
    __syncthreads();
    // V^T: thread (dr = tid&63, kg = tid>>6) covers kv = 16kg..16kg+15 at d = dr
    {
        const int dr = tid & 63, kg = tid >> 6;
        float x[16];
        #pragma unroll
        for (int j = 0; j < 16; ++j) x[j] = vt[16 * kg + j][dr];
        uint4 g0, g1;
        g0.x = pkbf(x[0],  x[1]);  g0.y = pkbf(x[2],  x[3]);
        g0.z = pkbf(x[4],  x[5]);  g0.w = pkbf(x[6],  x[7]);
        g1.x = pkbf(x[8],  x[9]);  g1.y = pkbf(x[10], x[11]);
        g1.z = pkbf(x[12], x[13]); g1.w = pkbf(x[14], x[15]);
        unsigned short* out = Vz + ((size_t)(h * 64 + tau)) * 4096 + dr * 64;
        *reinterpret_cast<uint4*>(out + (((2 * kg)     ^ (dr & 7)) * 8)) = g0;
        *reinterpret_cast<uint4*>(out + (((2 * kg + 1) ^ (dr & 7)) * 8)) = g1;
    }
}

// ---------------- main kernel
// R4 change: occupancy 3->4 blocks/CU. LDS was the binder (48KB -> 3/CU).
// V(it) isn't read until the PV phase, so V only needs prefetch distance 1:
// asymmetric buffering K 3-deep (24KB) + V 2-deep (16KB) = 40KB -> 4/CU.
// Per-iter issue order V(it+1) then K(it+2) makes s_waitcnt vmcnt(2) leave
// exactly K(it+2) in flight across the barrier (V(it)/K(it+1) complete).
// Grid is now exact-fill (1024 blocks = 4x256): no refill, so per-CU work
// balance is static. Remap so each CU's presumed set {r, r+16, r+32, r+48}
// becomes the adjacent-pair balanced set {2g, 2g+1, 62-2g, 63-2g}: every
// CU sums to exactly 130 iters and the two long blocks co-reside through
// the tail (concurrency >=2 for ~62 iters).
__global__ __launch_bounds__(256, 4)
void fa_main(const float* __restrict__ Q, const unsigned short* __restrict__ Kz,
             const unsigned short* __restrict__ Vz, const int* __restrict__ causal_p,
             float* __restrict__ O) {
    __shared__ __align__(16) unsigned char smem[40960];
    unsigned short* Klds = (unsigned short*)smem;              // 3 x 8 KB
    unsigned short* Vlds = (unsigned short*)(smem + 24576);    // 2 x 8 KB
    unsigned short* Qlds = (unsigned short*)(smem + 16384);    // prologue overlay on K buf2
    float* Lred = (float*)smem;                                // epilogue overlay, 18432 B
    float* Lsum = (float*)(smem + 18432);                      // epilogue overlay, 512 B

    const int bid = blockIdx.x;
    const int h   = bid & 15;
    const int r4  = bid >> 4;              // 0..63
    const int sl  = r4 >> 4;               // dispatch slot 0..3
    const int g4  = r4 & 15;
    int x;                                  // balanced adjacent-pair sets per CU
    if      (sl == 0) x = 2 * g4;
    else if (sl == 1) x = 2 * g4 + 1;
    else if (sl == 2) x = 62 - 2 * g4;
    else              x = 63 - 2 * g4;
    const int q0  = x * 64;

    const int tid = threadIdx.x;
    const int wv  = tid >> 6;
    const int wq  = wv & 1;                // q-half owned by this wave
    const int wk  = wv >> 1;               // kv-half owned by this wave
    const int ln  = tid & 63;
    const int c16 = ln & 15;
    const int qd  = ln >> 4;
    const int causal = causal_p[0];

    const float SC = 0.18033688011112042f;  // (1/sqrt(64)) * log2(e)

    // glds pointers (per-lane; lane0 value is the wave-uniform LDS base)
    const char* kg = (const char*)Kz + (size_t)h * 64 * 8192 + wv * 2048 + ln * 16;
    const char* vg = (const char*)Vz + (size_t)h * 64 * 8192 + wv * 2048 + ln * 16;
    char* kl = (char*)smem + wv * 2048 + ln * 16;
    char* vl = (char*)smem + 24576 + wv * 2048 + ln * 16;

#define GK_TILE(IT, BUF) do {                                    \
    const char* ks_ = kg + (size_t)(IT) * 8192;                  \
    char* kd_ = kl + (BUF) * 8192;                               \
    gl16(ks_, kd_); gl16(ks_ + 1024, kd_ + 1024);                \
} while (0)
#define GV_TILE(IT, BUF) do {                                    \
    const char* vs_ = vg + (size_t)(IT) * 8192;                  \
    char* vd_ = vl + (BUF) * 8192;                               \
    gl16(vs_, vd_); gl16(vs_ + 1024, vd_ + 1024);                \
} while (0)

    const int nIter = causal ? (x + 1) : (S_LEN / 64);

    // prologue fetches (all drained by the first __syncthreads)
    GV_TILE(0, 0);
    GK_TILE(0, 0);
    if (nIter > 1) GK_TILE(1, 1);

    // ---- stage Q tile (scaled fp32->bf16, swizzled) into K-buf2 overlay ----
    {
        const int r = tid >> 2, gg = tid & 3;
        const float* qp = Q + ((size_t)(q0 + r) * NH + h) * HD + 16 * gg;
        const float4 a = *reinterpret_cast<const float4*>(qp);
        const float4 b = *reinterpret_cast<const float4*>(qp + 4);
        const float4 c = *reinterpret_cast<const float4*>(qp + 8);
        const float4 d = *reinterpret_cast<const float4*>(qp + 12);
        uint4 f0, f1;
        f0.x = pkbf(a.x * SC, a.y * SC); f0.y = pkbf(a.z * SC, a.w * SC);
        f0.z = pkbf(b.x * SC, b.y * SC); f0.w = pkbf(b.z * SC, b.w * SC);
        f1.x = pkbf(c.x * SC, c.y * SC); f1.y = pkbf(c.z * SC, c.w * SC);
        f1.z = pkbf(d.x * SC, d.y * SC); f1.w = pkbf(d.z * SC, d.w * SC);
        unsigned short* out = Qlds + r * 64;
        *reinterpret_cast<uint4*>(out + (((2 * gg)     ^ (r & 7)) * 8)) = f0;
        *reinterpret_cast<uint4*>(out + (((2 * gg + 1) ^ (r & 7)) * 8)) = f1;
    }

    floatx4 acc[4][2];   // [md (d-tile)][t_l (q-tile in wq half)], partial O^T over wk's kv
    #pragma unroll
    for (int m = 0; m < 4; ++m)
        #pragma unroll
        for (int t = 0; t < 2; ++t) acc[m][t] = floatx4{0.f, 0.f, 0.f, 0.f};
    float lacc[2] = {0.f, 0.f};

    const int e7 = c16 & 7;
    const int o0 = (qd ^ e7) * 8;              // elems, x32 frag chunk 0
    const int o1 = ((4 + qd) ^ e7) * 8;        // elems, x32 frag chunk 1
    // V^T b64 frag offsets for kv sub-tiles ks=0,1 of this wave's kv half
    const int vo0 = ((4 * wk + 0 + (qd >> 1)) ^ e7) * 8 + (qd & 1) * 4;
    const int vo1 = ((4 * wk + 2 + (qd >> 1)) ^ e7) * 8 + (qd & 1) * 4;

    __syncthreads();   // Q visible + K0,K1,V0 landed (full drain; once per block)

    // ---- hoist loop-invariant Q fragments (this wave's 32 q rows, 16 VGPR) ----
    bf16x8 qh0[2], qh1[2];
    #pragma unroll
    for (int t = 0; t < 2; ++t) {
        const unsigned short* qrow = Qlds + (16 * (2 * wq + t) + c16) * 64;
        qh0[t] = *reinterpret_cast<const bf16x8*>(qrow + o0);
        qh1[t] = *reinterpret_cast<const bf16x8*>(qrow + o1);
    }
    __syncthreads();   // all waves done hoisting before iter-0 GK(2) hits buf2

    int kbr = 0;       // K buffer holding tile it       (= it % 3)
    int kb2 = 2;       // K buffer for tile it+2         (= (it+2) % 3)
    for (int it = 0; it < nIter; ++it) {
        // need K(it), V(it) complete. Newest 2 outstanding loads are K(it+1)
        // (issue order below: V first, K last) -> counted wait keeps K flying.
        if (it + 1 < nIter) {
            asm volatile("s_waitcnt vmcnt(2)" ::: "memory");
        } else {
            asm volatile("s_waitcnt vmcnt(0)" ::: "memory");
        }
        __builtin_amdgcn_s_barrier();

        // issue V before K so K(it+2) is the newest (survives next wait)
        if (it + 1 < nIter) GV_TILE(it + 1, (it + 1) & 1);
        if (it + 2 < nIter) GK_TILE(it + 2, kb2);

        const unsigned short* Kb = Klds + kbr * 4096;
        const unsigned short* Vb = Vlds + (it & 1) * 4096;

        // K fragments: this wave's kv half, two 16-row sub-tiles
        bf16x8 kf0[2], kf1[2];
        #pragma unroll
        for (int ks = 0; ks < 2; ++ks) {
            const unsigned short* krow = Kb + (32 * wk + 16 * ks + c16) * 64;
            kf0[ks] = *reinterpret_cast<const bf16x8*>(krow + o0);
            kf1[ks] = *reinterpret_cast<const bf16x8*>(krow + o1);
        }

        const bool maskit = (causal != 0) && (it == nIter - 1);

        // S^T = K Q^T per (ks, t); exp2 -> P in B-layout for x16 PV
        BF4 pf[2][2];   // [ks][t]
        #pragma unroll
        for (int ks = 0; ks < 2; ++ks) {
            const int kvb = 32 * wk + 16 * ks + 4 * qd;   // kv-local of reg i=0
            #pragma unroll
            for (int t = 0; t < 2; ++t) {
                floatx4 st = __builtin_amdgcn_mfma_f32_16x16x32_bf16(
                    kf0[ks], qh0[t], floatx4{0.f, 0.f, 0.f, 0.f}, 0, 0, 0);
                st = __builtin_amdgcn_mfma_f32_16x16x32_bf16(kf1[ks], qh1[t], st, 0, 0, 0);
                const int qloc = 16 * (2 * wq + t) + c16;
                float p[4];
                #pragma unroll
                for (int i = 0; i < 4; ++i) {
                    float sv = st[i];
                    if (maskit && (kvb + i > qloc)) sv = -1e30f;
                    p[i] = __builtin_amdgcn_exp2f(sv);
                }
                lacc[t] += (p[0] + p[1]) + (p[2] + p[3]);
                pf[ks][t].d[0] = pkbf(p[0], p[1]);
                pf[ks][t].d[1] = pkbf(p[2], p[3]);
            }
        }

        // O^T(partial) += V^T[:, kv_wk] P^T[kv_wk, :]  (x16, k=16 per sub-tile)
        #pragma unroll
        for (int md = 0; md < 4; ++md) {
            const unsigned short* vrow = Vb + (16 * md + c16) * 64;
            BF4 vf0, vf1;
            *reinterpret_cast<uint2*>(&vf0.d[0]) = *reinterpret_cast<const uint2*>(vrow + vo0);
            *reinterpret_cast<uint2*>(&vf1.d[0]) = *reinterpret_cast<const uint2*>(vrow + vo1);
            #pragma unroll
            for (int t = 0; t < 2; ++t) {
                acc[md][t] = mfma16(vf0.s, pf[0][t].s, acc[md][t]);
                acc[md][t] = mfma16(vf1.s, pf[1][t].s, acc[md][t]);
            }
        }

        kbr = (kbr == 2) ? 0 : kbr + 1;
        kb2 = (kb2 == 2) ? 0 : kb2 + 1;
    }

    __syncthreads();   // all waves out of the K/V buffers before epilogue overlay

    // ---- epilogue: pairwise (wk=0 + wk=1) reduction via LDS ----
    // Lane (c16,qd) reg (md,t,i) holds O^T[d=16md+4qd+i][q=16(2wq+t)+c16] partial.
    #pragma unroll
    for (int t = 0; t < 2; ++t) {
        float lt = lacc[t];
        lt += __shfl_xor(lt, 16);
        lt += __shfl_xor(lt, 32);
        if (qd == 0) Lsum[wk * 64 + wq * 32 + t * 16 + c16] = lt;
    }
    if (wk == 0) {
        float* Lw = Lred + (wq * 64 + ln) * 36;
        #pragma unroll
        for (int md = 0; md < 4; ++md)
            #pragma unroll
            for (int t = 0; t < 2; ++t)
                *reinterpret_cast<floatx4*>(&Lw[(md * 2 + t) * 4]) = acc[md][t];
    }
    __syncthreads();
    if (wk == 1) {
        const float* Lr = Lred + (wq * 64 + ln) * 36;
        float inv[2];
        #pragma unroll
        for (int t = 0; t < 2; ++t) {
            const int qidx = wq * 32 + t * 16 + c16;
            inv[t] = 1.0f / (Lsum[qidx] + Lsum[64 + qidx]);
        }
        #pragma unroll
        for (int md = 0; md < 4; ++md)
            #pragma unroll
            for (int t = 0; t < 2; ++t) {
                const floatx4 b = *reinterpret_cast<const floatx4*>(&Lr[(md * 2 + t) * 4]);
                const floatx4 a = acc[md][t];
                floatx4 o;
                o[0] = (a[0] + b[0]) * inv[t];
                o[1] = (a[1] + b[1]) * inv[t];
                o[2] = (a[2] + b[2]) * inv[t];
                o[3] = (a[3] + b[3]) * inv[t];
                const int q = q0 + 16 * (2 * wq + t) + c16;
                *reinterpret_cast<floatx4*>(O + ((size_t)q * NH + h) * HD + 16 * md + 4 * qd) = o;
            }
    }
}

extern "C" void kernel_launch(void* const* d_in, const int* in_sizes, int n_in,
                              void* d_out, int out_size, void* d_ws, size_t ws_size,
                              hipStream_t stream) {
    const float* q = (const float*)d_in[0];
    const float* k = (const float*)d_in[1];
    const float* v = (const float*)d_in[2];
    const int* causal = (const int*)d_in[3];
    float* out = (float*)d_out;
    unsigned short* Kz = (unsigned short*)d_ws;                      // 8 MB
    unsigned short* Vz = Kz + (size_t)NH * 64 * 4096;                // 8 MB
    pp_kv<<<dim3(64 * NH), dim3(256), 0, stream>>>(k, v, Kz, Vz);
    fa_main<<<dim3(64 * NH), dim3(256), 0, stream>>>(q, Kz, Vz, causal, out);
}

// Round 5
// 142.327 us; speedup vs baseline: 1.0571x; 1.0571x over previous
//
#include <hip/hip_runtime.h>
#include <stdint.h>

#define S_LEN 4096
#define NH    16
#define HD    64
#define RSTR  (NH * HD)   // seq-row stride in floats
#define LRSTR 18          // epilogue reduction row stride (floats)

typedef __attribute__((ext_vector_type(8))) __bf16 bf16x8;
typedef __attribute__((ext_vector_type(4))) short short4v;
typedef __attribute__((ext_vector_type(4))) float floatx4;

union BF4 { unsigned short u[4]; unsigned d[2]; short4v s; };

// pack two f32 -> bf16x2 (round-half-up) in one v_perm_b32
__device__ __forceinline__ unsigned pkbf(float a, float b) {
    unsigned ua = __builtin_bit_cast(unsigned, a) + 0x8000u;
    unsigned ub = __builtin_bit_cast(unsigned, b) + 0x8000u;
    return __builtin_amdgcn_perm(ub, ua, 0x07060302u);
}

__device__ __forceinline__ floatx4 mfma16(short4v a, short4v b, floatx4 c) {
#if __has_builtin(__builtin_amdgcn_mfma_f32_16x16x16bf16_1k)
    return __builtin_amdgcn_mfma_f32_16x16x16bf16_1k(a, b, c, 0, 0, 0);
#else
    floatx4 d;
    asm volatile("v_mfma_f32_16x16x16_bf16 %0, %1, %2, %3\n\ts_nop 7\n\ts_nop 7"
                 : "=v"(d) : "v"(a), "v"(b), "v"(c));
    return d;
#endif
}

// async global->LDS, 16B/lane
__device__ __forceinline__ void gl16(const void* g, void* l) {
#if __has_builtin(__builtin_amdgcn_global_load_lds)
    __builtin_amdgcn_global_load_lds((const __attribute__((address_space(1))) unsigned int*)g,
                                     (__attribute__((address_space(3))) unsigned int*)l, 16, 0, 0);
#else
    *(uint4*)l = *(const uint4*)g;
#endif
}

// ---------------- preprocess: K -> bf16 swizzled tiles, V -> V^T bf16 swizzled tiles
// tile(h,tau) = 64x64 bf16 = 8 KB, contiguous; element (r, c) at
// r*64 + ((c>>3)^(r&7))*8 + (c&7)  (XOR granule swizzle)
__global__ __launch_bounds__(256)
void pp_kv(const float* __restrict__ K, const float* __restrict__ V,
           unsigned short* __restrict__ Kz, unsigned short* __restrict__ Vz) {
    __shared__ __align__(16) float vt[64][68];   // +4 pad: 16B-aligned rows, read conflict-free
    const int bid = blockIdx.x;
    const int h   = bid & 15;
    const int tau = bid >> 4;
    const int tid = threadIdx.x;
    // K: thread (r = tid>>2, gg = tid&3) covers d = 16gg..16gg+15 of row r
    {
        const int r = tid >> 2, gg = tid & 3;
        const float* kp = K + ((size_t)(64 * tau + r) * NH + h) * HD + 16 * gg;
        const float4 a = *reinterpret_cast<const float4*>(kp);
        const float4 b = *reinterpret_cast<const float4*>(kp + 4);
        const float4 c = *reinterpret_cast<const float4*>(kp + 8);
        const float4 d = *reinterpret_cast<const float4*>(kp + 12);
        uint4 f0, f1;
        f0.x = pkbf(a.x, a.y); f0.y = pkbf(a.z, a.w);
        f0.z = pkbf(b.x, b.y); f0.w = pkbf(b.z, b.w);
        f1.x = pkbf(c.x, c.y); f1.y = pkbf(c.z, c.w);
        f1.z = pkbf(d.x, d.y); f1.w = pkbf(d.z, d.w);
        unsigned short* out = Kz + ((size_t)(h * 64 + tau)) * 4096 + r * 64;
        *reinterpret_cast<uint4*>(out + (((2 * gg)     ^ (r & 7)) * 8)) = f0;
        *reinterpret_cast<uint4*>(out + (((2 * gg + 1) ^ (r & 7)) * 8)) = f1;
    }
    // V: coalesced row loads -> LDS
    {
        const int r = tid >> 2, ch = tid & 3;
        const float* vrow = V + ((size_t)(64 * tau + r) * NH + h) * HD + 4 * ch;
        #pragma unroll
        for (int k2 = 0; k2 < 4; ++k2)
            *reinterpret_cast<float4*>(&vt[r][4 * ch + 16 * k2]) =
                *reinterpret_cast<const float4*>(vrow + 16 * k2);
    }
    __syncthreads();
    // V^T: thread (dr = tid&63, kg = tid>>6) covers kv = 16kg..16kg+15 at d = dr
    {
        const int dr = tid & 63, kg = tid >> 6;
        float x[16];
        #pragma unroll
        for (int j = 0; j < 16; ++j) x[j] = vt[16 * kg + j][dr];
        uint4 g0, g1;
        g0.x = pkbf(x[0],  x[1]);  g0.y = pkbf(x[2],  x[3]);
        g0.z = pkbf(x[4],  x[5]);  g0.w = pkbf(x[6],  x[7]);
        g1.x = pkbf(x[8],  x[9]);  g1.y = pkbf(x[10], x[11]);
        g1.z = pkbf(x[12], x[13]); g1.w = pkbf(x[14], x[15]);
        unsigned short* out = Vz + ((size_t)(h * 64 + tau)) * 4096 + dr * 64;
        *reinterpret_cast<uint4*>(out + (((2 * kg)     ^ (dr & 7)) * 8)) = g0;
        *reinterpret_cast<uint4*>(out + (((2 * kg + 1) ^ (dr & 7)) * 8)) = g1;
    }
}

// ---------------- main kernel
// R5: recombination. R2's 2q x 2kv split made wq-pair waves read IDENTICAL
// K/V fragments (kf/vf independent of wq) -> 2x duplicated ds_read traffic
// (~700 cyc/block-iter LDS pipe incl. conflicts, a 38 us/CU floor). Revert
// to the R1 4xKV split (each wave owns a disjoint 16-kv slice: 2 b128 K +
// 4 b64 V reads/wave-iter, ~420 cyc/block-iter) while KEEPING R3's
// latency-tolerant pipeline: 3-deep K/V buffers (48 KB), prefetch distance
// 2, counted s_waitcnt vmcnt(4) + raw s_barrier per iter (vmcnt(0) only on
// the last). Plain LPT dispatch order (longest first; R4's "balanced sets"
// remap inverted LPT under refill and regressed 15%).
__global__ __launch_bounds__(256, 3)
void fa_main(const float* __restrict__ Q, const unsigned short* __restrict__ Kz,
             const unsigned short* __restrict__ Vz, const int* __restrict__ causal_p,
             float* __restrict__ O) {
    __shared__ __align__(16) unsigned char smem[49152];
    unsigned short* Klds = (unsigned short*)smem;              // 3 x 8 KB
    unsigned short* Vlds = (unsigned short*)(smem + 24576);    // 3 x 8 KB
    unsigned short* Qlds = (unsigned short*)(smem + 16384);    // prologue overlay on K buf2
    float* Lsum = (float*)smem;                                // epilogue overlay, 1 KB
    float* Lred = (float*)(smem + 16384);                      // epilogue overlay, 18432 B

    const int bid = blockIdx.x;
    const int h   = bid & 15;
    const int x   = 63 - (bid >> 4);       // longest-first dispatch order (LPT)
    const int q0  = x * 64;

    const int tid = threadIdx.x;
    const int wv  = tid >> 6;
    const int ln  = tid & 63;
    const int c16 = ln & 15;
    const int qd  = ln >> 4;
    const int causal = causal_p[0];

    const float SC = 0.18033688011112042f;  // (1/sqrt(64)) * log2(e)

    // glds pointers (per-lane; lane0 value is the wave-uniform LDS base)
    const char* kg = (const char*)Kz + (size_t)h * 64 * 8192 + wv * 2048 + ln * 16;
    const char* vg = (const char*)Vz + (size_t)h * 64 * 8192 + wv * 2048 + ln * 16;
    char* kl = (char*)smem + wv * 2048 + ln * 16;
    char* vl = (char*)smem + 24576 + wv * 2048 + ln * 16;

#define GLDS_TILE(IT, BUF) do {                                  \
    const char* ks_ = kg + (size_t)(IT) * 8192;                  \
    const char* vs_ = vg + (size_t)(IT) * 8192;                  \
    char* kd_ = kl + (BUF) * 8192;                               \
    char* vd_ = vl + (BUF) * 8192;                               \
    gl16(ks_, kd_); gl16(ks_ + 1024, kd_ + 1024);                \
    gl16(vs_, vd_); gl16(vs_ + 1024, vd_ + 1024);                \
} while (0)

    // start K/V tile 0/1 fetch immediately (overlaps with Q staging)
    GLDS_TILE(0, 0);
    GLDS_TILE(1, 1);

    // ---- stage Q tile (scaled fp32->bf16, swizzled) into K-buf2 overlay ----
    {
        const int r = tid >> 2, gg = tid & 3;
        const float* qp = Q + ((size_t)(q0 + r) * NH + h) * HD + 16 * gg;
        const float4 a = *reinterpret_cast<const float4*>(qp);
        const float4 b = *reinterpret_cast<const float4*>(qp + 4);
        const float4 c = *reinterpret_cast<const float4*>(qp + 8);
        const float4 d = *reinterpret_cast<const float4*>(qp + 12);
        uint4 f0, f1;
        f0.x = pkbf(a.x * SC, a.y * SC); f0.y = pkbf(a.z * SC, a.w * SC);
        f0.z = pkbf(b.x * SC, b.y * SC); f0.w = pkbf(b.z * SC, b.w * SC);
        f1.x = pkbf(c.x * SC, c.y * SC); f1.y = pkbf(c.z * SC, c.w * SC);
        f1.z = pkbf(d.x * SC, d.y * SC); f1.w = pkbf(d.z * SC, d.w * SC);
        unsigned short* out = Qlds + r * 64;
        *reinterpret_cast<uint4*>(out + (((2 * gg)     ^ (r & 7)) * 8)) = f0;
        *reinterpret_cast<uint4*>(out + (((2 * gg + 1) ^ (r & 7)) * 8)) = f1;
    }

    const int nIter = causal ? (x + 1) : (S_LEN / 64);

    floatx4 acc[4][4];   // [md (d-tile)][t (q-tile)], partial O^T over this wave's kv
    #pragma unroll
    for (int m = 0; m < 4; ++m)
        #pragma unroll
        for (int t = 0; t < 4; ++t) acc[m][t] = floatx4{0.f, 0.f, 0.f, 0.f};
    float lacc[4] = {0.f, 0.f, 0.f, 0.f};

    const int e7 = c16 & 7;
    const int o0 = (qd ^ e7) * 8;              // elems, x32 frag chunk 0
    const int o1 = ((4 + qd) ^ e7) * 8;        // elems, x32 frag chunk 1
    const int vo = ((2 * wv + (qd >> 1)) ^ e7) * 8 + (qd & 1) * 4;  // V^T b64 frag
    const int mlhs = 16 * wv + 4 * qd;         // causal: kv-local of reg i=0

    __syncthreads();   // Q visible + tiles 0,1 landed (full drain; once per block)

    // ---- hoist loop-invariant Q fragments (all 64 q rows, 32 VGPR) ----
    bf16x8 qh0[4], qh1[4];
    #pragma unroll
    for (int t = 0; t < 4; ++t) {
        const unsigned short* qrow = Qlds + (16 * t + c16) * 64;
        qh0[t] = *reinterpret_cast<const bf16x8*>(qrow + o0);
        qh1[t] = *reinterpret_cast<const bf16x8*>(qrow + o1);
    }
    __syncthreads();   // all waves done hoisting before iter-0 GLDS(2) hits buf2

    int br = 0;        // buffer holding tile it      (= it % 3)
    int b2 = 2;        // buffer for tile it+2        (= (it+2) % 3)
    for (int it = 0; it < nIter; ++it) {
        // tile `it` was issued >=2 iterations ago; tile it+1 (4 loads) may
        // still be in flight -> counted wait keeps it flying.
        if (it == nIter - 1) {
            asm volatile("s_waitcnt vmcnt(0)" ::: "memory");
        } else {
            asm volatile("s_waitcnt vmcnt(4)" ::: "memory");
        }
        __builtin_amdgcn_s_barrier();

        if (it + 2 < nIter) GLDS_TILE(it + 2, b2);

        const unsigned short* Kb = Klds + br * 4096;
        const unsigned short* Vb = Vlds + br * 4096;

        // K fragment: rows kv = 16wv + c16 (this wave's disjoint kv slice)
        const unsigned short* krow = Kb + (16 * wv + c16) * 64;
        const bf16x8 kf0 = *reinterpret_cast<const bf16x8*>(krow + o0);
        const bf16x8 kf1 = *reinterpret_cast<const bf16x8*>(krow + o1);

        const bool maskit = (causal != 0) && (it == nIter - 1);

        // S^T = K Q^T per q-tile t; exp2 -> P directly in B-layout for x16 PV
        BF4 pf[4];
        #pragma unroll
        for (int t = 0; t < 4; ++t) {
            floatx4 st = __builtin_amdgcn_mfma_f32_16x16x32_bf16(
                kf0, qh0[t], floatx4{0.f, 0.f, 0.f, 0.f}, 0, 0, 0);
            st = __builtin_amdgcn_mfma_f32_16x16x32_bf16(kf1, qh1[t], st, 0, 0, 0);
            float p[4];
            #pragma unroll
            for (int i = 0; i < 4; ++i) {
                float sv = st[i];
                if (maskit && (mlhs + i > 16 * t + c16)) sv = -1e30f;
                p[i] = __builtin_amdgcn_exp2f(sv);
            }
            lacc[t] += (p[0] + p[1]) + (p[2] + p[3]);
            pf[t].d[0] = pkbf(p[0], p[1]);
            pf[t].d[1] = pkbf(p[2], p[3]);
        }

        // O^T(partial) += V^T[:, kv_wv] P^T[kv_wv, :]  (x16, k=16)
        #pragma unroll
        for (int md = 0; md < 4; ++md) {
            BF4 vf;
            const unsigned short* vrow = Vb + (16 * md + c16) * 64 + vo;
            *reinterpret_cast<uint2*>(&vf.d[0]) = *reinterpret_cast<const uint2*>(vrow);
            #pragma unroll
            for (int t = 0; t < 4; ++t)
                acc[md][t] = mfma16(vf.s, pf[t].s, acc[md][t]);
        }

        br = (br == 2) ? 0 : br + 1;
        b2 = (b2 == 2) ? 0 : b2 + 1;
    }

    __syncthreads();   // all waves out of the K/V buffers before epilogue overlay

    // ---- epilogue: cross-wave reduction of partial O^T and l via LDS ----
    // Lane (c16,qd) reg (md,t,i) holds O^T[d=16md+4qd+i][q=16t+c16].
    #pragma unroll
    for (int t = 0; t < 4; ++t) {
        float lt = lacc[t];
        lt += __shfl_xor(lt, 16);
        lt += __shfl_xor(lt, 32);
        if (qd == 0) Lsum[wv * 64 + t * 16 + c16] = lt;
    }

    const int qi  = tid & 63;          // reader: owns q row q0+qi
    const int dg  = tid >> 6;          // reader: d sub-block
    const int lnr = 16 * dg + (qi & 15);
    const int jb  = 4 * (qi >> 4);
    float* orow = O + ((size_t)(q0 + qi) * NH + h) * HD;
    float inv = 0.f;

    for (int md = 0; md < 4; ++md) {
        float* Lw = Lred + (wv * 64 + ln) * LRSTR;
        #pragma unroll
        for (int t = 0; t < 4; ++t) {
            float2 w0; w0.x = acc[md][t][0]; w0.y = acc[md][t][1];
            float2 w1; w1.x = acc[md][t][2]; w1.y = acc[md][t][3];
            *reinterpret_cast<float2*>(&Lw[4 * t])     = w0;
            *reinterpret_cast<float2*>(&Lw[4 * t + 2]) = w1;
        }
        __syncthreads();
        if (md == 0) {
            const float l = Lsum[qi] + Lsum[64 + qi] + Lsum[128 + qi] + Lsum[192 + qi];
            inv = 1.0f / l;
        }
        float s0 = 0.f, s1 = 0.f, s2 = 0.f, s3 = 0.f;
        #pragma unroll
        for (int w = 0; w < 4; ++w) {
            const float* Lr = Lred + (w * 64 + lnr) * LRSTR + jb;
            s0 += Lr[0]; s1 += Lr[1]; s2 += Lr[2]; s3 += Lr[3];
        }
        floatx4 o; o[0] = s0 * inv; o[1] = s1 * inv; o[2] = s2 * inv; o[3] = s3 * inv;
        *reinterpret_cast<floatx4*>(orow + 16 * md + 4 * dg) = o;
        __syncthreads();
    }
}

extern "C" void kernel_launch(void* const* d_in, const int* in_sizes, int n_in,
                              void* d_out, int out_size, void* d_ws, size_t ws_size,
                              hipStream_t stream) {
    const float* q = (const float*)d_in[0];
    const float* k = (const float*)d_in[1];
    const float* v = (const float*)d_in[2];
    const int* causal = (const int*)d_in[3];
    float* out = (float*)d_out;
    unsigned short* Kz = (unsigned short*)d_ws;                      // 8 MB
    unsigned short* Vz = Kz + (size_t)NH * 64 * 4096;                // 8 MB
    pp_kv<<<dim3(64 * NH), dim3(256), 0, stream>>>(k, v, Kz, Vz);
    fa_main<<<dim3(64 * NH), dim3(256), 0, stream>>>(q, Kz, Vz, causal, out);
}